// Round 1
// baseline (333.705 us; speedup 1.0000x reference)
//
#include <hip/hip_runtime.h>

#define N_PMT 180
#define N_PMT4 45          // 180 floats = 45 float4 per vis row (720 B, 16B-aligned)
#define N_CLUSTERS 128
#define NBINS 512          // sort buckets: vox >> 9
#define BPC 16             // gather blocks per cluster (chunk = 512 points)
#define BLOCK 256
#define NWAVE (BLOCK / 64)
#define PIPE 4             // software-pipeline depth (rows in flight)
#define SORT_T 1024
#define SORT_CAP 8192      // max points per cluster held in LDS (64 KB)

// ---- workspace layout (bytes) ----
// 0       : int   offsC[N_CLUSTERS+1]
// 1024    : float dxc[N_CLUSTERS]        (fallback path only)
// 2048    : uint2 sorted[n]  (vox, q_bits) bucket-sorted within cluster

// ---------------- fused voxelize + counting sort, one block per cluster ------
// Computes its own cluster offset (no prep dependency), clips dx inline,
// reads batch ONCE, sorts (vox,q) by vox>>9 via LDS hist+scan, writes sorted.
__global__ __launch_bounds__(SORT_T) void k_voxsort(
    const float4* __restrict__ batch,
    const float*  __restrict__ dx,
    const int*    __restrict__ sizes,
    const float*  __restrict__ dx_ranges,
    int*          __restrict__ offsC,
    uint2*        __restrict__ sorted) {

    __shared__ uint2 svq[SORT_CAP];                       // 64 KB
    __shared__ int hist[NBINS], sa[NBINS], sb[NBINS], cur[NBINS];  // 8 KB
    __shared__ int sSz[N_CLUSTERS];
    __shared__ int sE0, sCnt;

    const int c = blockIdx.x, t = threadIdx.x;
    if (t < N_CLUSTERS) sSz[t] = sizes[t];
    if (t < NBINS) hist[t] = 0;
    __syncthreads();
    if (t == 0) {
        int acc = 0;
        for (int i = 0; i < c; ++i) acc += sSz[i];
        sE0 = acc; sCnt = sSz[c];
        offsC[c] = acc;                                   // k_gather reads these
        if (c == N_CLUSTERS - 1) offsC[N_CLUSTERS] = acc + sSz[c];
    }
    __syncthreads();
    const int e0 = sE0, cnt = sCnt;
    const float lo = dx_ranges[2 * c], hi = dx_ranges[2 * c + 1];
    const float dxcc = fminf(fmaxf(dx[c], lo), hi);
    const bool fits = (cnt <= SORT_CAP);                  // wave-uniform

    for (int i = t; i < cnt; i += SORT_T) {
        float4 pd = batch[e0 + i];
        int ix = max(0, min(63, (int)floorf(pd.x + dxcc)));
        int iy = max(0, min(63, (int)floorf(pd.y)));
        int iz = max(0, min(63, (int)floorf(pd.z)));
        unsigned vox = (unsigned)(ix + 64 * (iy + 64 * iz));
        if (fits) svq[i] = make_uint2(vox, __float_as_uint(pd.w));
        atomicAdd(&hist[vox >> 9], 1);
    }
    __syncthreads();
    if (t < NBINS) sa[t] = hist[t];
    __syncthreads();
    int* src = sa; int* dst = sb;
    for (int d = 1; d < NBINS; d <<= 1) {                 // Hillis-Steele inclusive scan
        if (t < NBINS) dst[t] = src[t] + (t >= d ? src[t - d] : 0);
        __syncthreads();
        int* tmp = src; src = dst; dst = tmp;
    }
    if (t < NBINS) cur[t] = src[t] - hist[t];             // exclusive
    __syncthreads();
    if (fits) {
        for (int i = t; i < cnt; i += SORT_T) {
            uint2 e = svq[i];
            int pos = atomicAdd(&cur[e.x >> 9], 1);
            sorted[e0 + pos] = e;
        }
    } else {                                              // general-size: re-read batch
        for (int i = t; i < cnt; i += SORT_T) {
            float4 pd = batch[e0 + i];
            int ix = max(0, min(63, (int)floorf(pd.x + dxcc)));
            int iy = max(0, min(63, (int)floorf(pd.y)));
            int iz = max(0, min(63, (int)floorf(pd.z)));
            unsigned vox = (unsigned)(ix + 64 * (iy + 64 * iz));
            int pos = atomicAdd(&cur[vox >> 9], 1);
            sorted[e0 + pos] = make_uint2(vox, __float_as_uint(pd.w));
        }
    }
}

__global__ __launch_bounds__(BLOCK) void k_gather(
    const uint2*  __restrict__ sorted,
    const float4* __restrict__ vis4,
    const int*    __restrict__ offsC,
    float* __restrict__ out) {

    const int c   = blockIdx.x & (N_CLUSTERS - 1);  // c fastest: same-region blocks adjacent
    const int sub = blockIdx.x >> 7;
    const int start = offsC[c], end = offsC[c + 1];
    const int count = end - start;
    const int chunk = (count + BPC - 1) / BPC;
    const int s0 = start + sub * chunk;
    const int s1 = min(s0 + chunk, end);

    const int wave = threadIdx.x >> 6, lane = threadIdx.x & 63;
    const int wtotal = s1 - s0;
    const int per = (wtotal + NWAVE - 1) / NWAVE;
    const int ws0 = s0 + wave * per;
    const int ws1 = min(ws0 + per, s1);

    const int lclamp = min(lane, N_PMT4 - 1);    // branchless: lanes 45..63 dup lane 44

    float4 accE = {0.f, 0.f, 0.f, 0.f};
    float4 accO = {0.f, 0.f, 0.f, 0.f};

    for (int base = ws0; base < ws1; base += 64) {
        const int p = base + lane;
        uint2 se = (p < ws1) ? sorted[p] : make_uint2(0u, 0u);  // pad: q=0
        const int   vox = (int)se.x;
        const float q   = __uint_as_float(se.y);

        // ---- software-pipelined row loads: issue batch j+1 before consuming batch j
        float4 rc[PIPE];
        #pragma unroll
        for (int jj = 0; jj < PIPE; ++jj) {
            const int v = __builtin_amdgcn_readlane(vox, jj);
            rc[jj] = vis4[(size_t)v * N_PMT4 + lclamp];
        }
        #pragma unroll
        for (int j0 = 0; j0 < 64; j0 += PIPE) {
            float4 rn[PIPE];
            if (j0 + PIPE < 64) {
                #pragma unroll
                for (int jj = 0; jj < PIPE; ++jj) {
                    const int v = __builtin_amdgcn_readlane(vox, j0 + PIPE + jj);
                    rn[jj] = vis4[(size_t)v * N_PMT4 + lclamp];
                }
            }
            #pragma unroll
            for (int jj = 0; jj < PIPE; ++jj) {
                const float qq = __uint_as_float(
                    __builtin_amdgcn_readlane(__float_as_uint(q), j0 + jj));
                if (jj & 1) {
                    accO.x = fmaf(rc[jj].x, qq, accO.x);
                    accO.y = fmaf(rc[jj].y, qq, accO.y);
                    accO.z = fmaf(rc[jj].z, qq, accO.z);
                    accO.w = fmaf(rc[jj].w, qq, accO.w);
                } else {
                    accE.x = fmaf(rc[jj].x, qq, accE.x);
                    accE.y = fmaf(rc[jj].y, qq, accE.y);
                    accE.z = fmaf(rc[jj].z, qq, accE.z);
                    accE.w = fmaf(rc[jj].w, qq, accE.w);
                }
            }
            #pragma unroll
            for (int jj = 0; jj < PIPE; ++jj) rc[jj] = rn[jj];  // renamed under full unroll
        }
    }

    // per-wave private LDS rows (no float LDS atomics), then one global atomic per PMT
    __shared__ float sacc[NWAVE][184];
    if (lane < N_PMT4) {
        sacc[wave][lane * 4 + 0] = accE.x + accO.x;
        sacc[wave][lane * 4 + 1] = accE.y + accO.y;
        sacc[wave][lane * 4 + 2] = accE.z + accO.z;
        sacc[wave][lane * 4 + 3] = accE.w + accO.w;
    }
    __syncthreads();
    for (int i = threadIdx.x; i < N_PMT; i += BLOCK) {
        float s = sacc[0][i] + sacc[1][i] + sacc[2][i] + sacc[3][i];
        atomicAdd(&out[c * N_PMT + i], s);
    }
}

// ---------------- fallback (unsorted point-major) ----------------
__global__ void prep_kernel(const float* __restrict__ dx,
                            const int* __restrict__ sizes,
                            const float* __restrict__ dx_ranges,
                            int* __restrict__ offsC,
                            float* __restrict__ dxc) {
    __shared__ int s[N_CLUSTERS];
    const int t = threadIdx.x;      // 128 threads
    s[t] = sizes[t];
    float lo = dx_ranges[2 * t];
    float hi = dx_ranges[2 * t + 1];
    dxc[t] = fminf(fmaxf(dx[t], lo), hi);
    __syncthreads();
    int acc = 0;
    for (int i = 0; i < t; ++i) acc += s[i];
    offsC[t] = acc;
    if (t == N_CLUSTERS - 1) offsC[N_CLUSTERS] = acc + s[t];
}

__global__ __launch_bounds__(BLOCK) void gather_kernel(
    const float4* __restrict__ batch,
    const float4* __restrict__ vis4,
    const int*    __restrict__ offsets,
    const float*  __restrict__ dxc,
    float* __restrict__ out) {
    const int b = blockIdx.x;
    const int c = b / 16, sub = b % 16;
    const int start = offsets[c], end = offsets[c + 1];
    const int count = end - start;
    const int chunk = (count + 15) / 16;
    const int s0 = start + sub * chunk;
    const int s1 = min(s0 + chunk, end);
    const int wave = threadIdx.x >> 6, lane = threadIdx.x & 63;
    const int wtotal = s1 - s0;
    const int per = (wtotal + NWAVE - 1) / NWAVE;
    const int ws0 = s0 + wave * per;
    const int ws1 = min(ws0 + per, s1);
    const float dxc_c = dxc[c];
    const bool active = (lane < N_PMT4);
    float4 accE = {0.f, 0.f, 0.f, 0.f};
    for (int base = ws0; base < ws1; base += 64) {
        const int p = base + lane;
        float q = 0.f; int vox = 0;
        if (p < ws1) {
            float4 pd = batch[p];
            int ix = max(0, min(63, (int)floorf(pd.x + dxc_c)));
            int iy = max(0, min(63, (int)floorf(pd.y)));
            int iz = max(0, min(63, (int)floorf(pd.z)));
            vox = ix + 64 * (iy + 64 * iz);
            q = pd.w;
        }
        #pragma unroll
        for (int j = 0; j < 64; ++j) {
            const int   v  = __builtin_amdgcn_readlane(vox, j);
            const float qj = __uint_as_float(__builtin_amdgcn_readlane(__float_as_uint(q), j));
            if (active) {
                float4 r = vis4[(size_t)v * N_PMT4 + lane];
                accE.x = fmaf(r.x, qj, accE.x);
                accE.y = fmaf(r.y, qj, accE.y);
                accE.z = fmaf(r.z, qj, accE.z);
                accE.w = fmaf(r.w, qj, accE.w);
            }
        }
    }
    __shared__ float sacc[N_PMT];
    for (int i = threadIdx.x; i < N_PMT; i += BLOCK) sacc[i] = 0.f;
    __syncthreads();
    if (active) {
        atomicAdd(&sacc[lane * 4 + 0], accE.x);
        atomicAdd(&sacc[lane * 4 + 1], accE.y);
        atomicAdd(&sacc[lane * 4 + 2], accE.z);
        atomicAdd(&sacc[lane * 4 + 3], accE.w);
    }
    __syncthreads();
    for (int i = threadIdx.x; i < N_PMT; i += BLOCK)
        atomicAdd(&out[c * N_PMT + i], sacc[i]);
}

extern "C" void kernel_launch(void* const* d_in, const int* in_sizes, int n_in,
                              void* d_out, int out_size, void* d_ws, size_t ws_size,
                              hipStream_t stream) {
    const float* dx        = (const float*)d_in[0];
    const float* batch     = (const float*)d_in[1];
    const int*   sizes     = (const int*)d_in[2];
    const float* dx_ranges = (const float*)d_in[3];
    const float* vis       = (const float*)d_in[4];
    float* out = (float*)d_out;
    char*  wsb = (char*)d_ws;
    const int n = in_sizes[1] / 4;   // total points

    int*   offsC  = (int*)(wsb + 0);
    float* dxc    = (float*)(wsb + 1024);
    uint2* sorted = (uint2*)(wsb + 2048);

    hipMemsetAsync(out, 0, (size_t)out_size * sizeof(float), stream);

    const size_t need = 2048ull + 8ull * (size_t)n;
    if (ws_size >= need) {
        k_voxsort<<<N_CLUSTERS, SORT_T, 0, stream>>>(
            (const float4*)batch, dx, sizes, dx_ranges, offsC, sorted);
        k_gather<<<N_CLUSTERS * BPC, BLOCK, 0, stream>>>(
            sorted, (const float4*)vis, offsC, out);
    } else {
        prep_kernel<<<1, N_CLUSTERS, 0, stream>>>(dx, sizes, dx_ranges, offsC, dxc);
        gather_kernel<<<N_CLUSTERS * 16, BLOCK, 0, stream>>>(
            (const float4*)batch, (const float4*)vis, offsC, dxc, out);
    }
}